// Round 10
// baseline (237.494 us; speedup 1.0000x reference)
//
#include <hip/hip_runtime.h>
#include <hip/hip_fp16.h>

// Problem constants (from the reference).
constexpr int S  = 51;   // seq positions
constexpr int V  = 64;   // vocab
constexpr int E  = 4;    // embedding dim
constexpr int H1 = 5;
constexpr int H2 = 7;
constexpr int D  = 64;   // output dim

constexpr int CH = 4;    // s-slices per staged chunk (8 KB each)
constexpr int NC = 13;   // ceil(51/4): chunks 0..11 have 4 slices, chunk 12 has 3

// ---------------------------------------------------------------------------
// Kernel 1: build fp16 table Y[s][v][d] = tanh(W3[s] @ h2(s,v) + b3[s]).
// Whole MLP depends only on (s, token): 3264 rows x 64 d, 408 KB fp16.
// ---------------------------------------------------------------------------
__global__ void build_table_kernel(const float* __restrict__ emb,
                                   const float* __restrict__ W1,
                                   const float* __restrict__ b1,
                                   const float* __restrict__ W2,
                                   const float* __restrict__ b2,
                                   const float* __restrict__ W3,
                                   const float* __restrict__ b3,
                                   __half* __restrict__ Y) {
  const int sv = blockIdx.x;     // sv = s*64 + v
  const int s  = sv >> 6;
  const int d  = threadIdx.x;    // 0..63

  float e[E];
#pragma unroll
  for (int i = 0; i < E; ++i) e[i] = emb[sv * E + i];

  float h1[H1];
#pragma unroll
  for (int h = 0; h < H1; ++h) {
    float a = b1[s * H1 + h];
#pragma unroll
    for (int i = 0; i < E; ++i) a = fmaf(W1[(s * H1 + h) * E + i], e[i], a);
    h1[h] = (a >= 0.f) ? a : 0.01f * a;   // leaky_relu
  }

  float h2[H2];
#pragma unroll
  for (int g = 0; g < H2; ++g) {
    float a = b2[s * H2 + g];
#pragma unroll
    for (int h = 0; h < H1; ++h) a = fmaf(W2[(s * H2 + g) * H1 + h], h1[h], a);
    h2[g] = (a >= 0.f) ? a : 0.01f * a;
  }

  float a = b3[s * D + d];
#pragma unroll
  for (int g = 0; g < H2; ++g) a = fmaf(W3[(s * D + d) * H2 + g], h2[g], a);

  Y[sv * D + d] = __float2half(tanhf(a));
}

// ---------------------------------------------------------------------------
// Kernel 2: out[b][d] = sum_s Y[s, x[b,s], d]  -- small-footprint LDS gather.
// 1024-thread blocks (16 waves, 8 rows/wave), 128 rows/block, 512 blocks,
// 64 KB LDS -> 2 blocks/CU, 32 waves/CU. Double-buffered chunks of 4
// s-slices (8 KB each); tokens live in registers (round-2 shfl scheme).
// Staging is async-split: issue global loads for chunk c+1, compute chunk c
// (hides L2 latency), ds_write late; one barrier per chunk.
// Inner step per (row,s): 1 shfl + 1 ds_read_b128 (bank-balanced: a row's 8
// octets cover all 32 banks) + 4 v_pk_add_f16; fp32 promote per chunk (4 s).
// ---------------------------------------------------------------------------
__global__ __launch_bounds__(1024, 8) void gather_sum_kernel(
    const int* __restrict__ x, const __half* __restrict__ Y,
    float* __restrict__ out) {
  __shared__ __align__(16) __half buf[2][CH * V * D];   // 2 x 32 KB

  const int tid   = threadIdx.x;
  const int lane  = tid & 63;
  const int li    = lane & 7;                    // d-octet 0..7
  const int wid   = tid >> 6;                    // wave 0..15
  const int row   = blockIdx.x * 128 + wid * 8 + (lane >> 3);

  // Pre-gather tokens as table-row BYTE offsets: tok[j] <-> s = j*8 + li.
  int tok[7];
#pragma unroll
  for (int j = 0; j < 7; ++j) {
    const int s = j * 8 + li;
    tok[j] = (s < S) ? (x[row * S + s] << 7) : 0;
  }

  const int rgsel = lane & 56;                   // rg<<3 (shfl group base)
  const int li16  = li << 4;                     // byte offset of 16B slice
  const char* bufb = (const char*)buf;

  float acc[8];
#pragma unroll
  for (int k = 0; k < 8; ++k) acc[k] = 0.f;

  // ---- prologue: stage chunk 0 (reg-staged, visibility via barrier c=0) ----
  {
    const uint4* src = (const uint4*)Y;          // chunk 0 at s=0
    uint4* dst = (uint4*)buf[0];
    dst[tid * 2]     = src[tid * 2];
    dst[tid * 2 + 1] = src[tid * 2 + 1];
  }

#pragma unroll
  for (int c = 0; c < NC; ++c) {
    __syncthreads();   // chunk c staged & previous reads of buf[c&1] done

    // Issue global loads for chunk c+1 (write to LDS AFTER compute).
    uint4 v0, v1;
    bool do_stage = false;
    int g0 = 0, g1 = 0;
    if (c + 1 < NC) {
      const int n16 = ((c + 1 < NC - 1) ? CH : 3) * 512;  // granules in chunk
      const uint4* src = (const uint4*)(Y + (c + 1) * CH * (V * D));
      g0 = tid * 2; g1 = tid * 2 + 1;
      do_stage = true;
      v0 = (g0 < n16) ? src[g0] : uint4{0, 0, 0, 0};
      v1 = (g1 < n16) ? src[g1] : uint4{0, 0, 0, 0};
    }

    // Compute chunk c from buf[c&1].
    __half2 a16[4];
#pragma unroll
    for (int k = 0; k < 4; ++k) a16[k] = __half2(__float2half(0.f), __float2half(0.f));

    const char* base = bufb + ((c & 1) << 15);
#pragma unroll
    for (int j = 0; j < CH; ++j) {
      const int s = c * CH + j;
      if (s < S) {
        const int t = __shfl(tok[s >> 3], rgsel | (s & 7), 64);  // t<<7
        const uint4 v = *(const uint4*)(base + ((j << 13) + t + li16));
        union { uint4 u; __half2 h[4]; } cv; cv.u = v;
#pragma unroll
        for (int k = 0; k < 4; ++k) a16[k] = __hadd2(a16[k], cv.h[k]);
      }
    }
#pragma unroll
    for (int k = 0; k < 4; ++k) {
      const float2 f = __half22float2(a16[k]);
      acc[2 * k]     += f.x;
      acc[2 * k + 1] += f.y;
    }

    // Late LDS write of chunk c+1 (loads have had ~1.5k cycles to land).
    if (do_stage) {
      uint4* dst = (uint4*)buf[(c + 1) & 1];
      dst[g0] = v0;
      dst[g1] = v1;
    }
  }

  // Epilogue: wave writes 8 rows x 256 B contiguous.
  float4* o = (float4*)(out + row * D + li * 8);
  o[0] = make_float4(acc[0], acc[1], acc[2], acc[3]);
  o[1] = make_float4(acc[4], acc[5], acc[6], acc[7]);
}

// ---------------------------------------------------------------------------
extern "C" void kernel_launch(void* const* d_in, const int* in_sizes, int n_in,
                              void* d_out, int out_size, void* d_ws, size_t ws_size,
                              hipStream_t stream) {
  const int*   x   = (const int*)d_in[0];
  const float* emb = (const float*)d_in[1];
  const float* W1  = (const float*)d_in[2];
  const float* b1  = (const float*)d_in[3];
  const float* W2  = (const float*)d_in[4];
  const float* b2  = (const float*)d_in[5];
  const float* W3  = (const float*)d_in[6];
  const float* b3  = (const float*)d_in[7];

  const int B = in_sizes[0] / S;          // 65536
  __half* Y = (__half*)d_ws;              // S*V*D halves = 417,792 bytes

  build_table_kernel<<<S * V, D, 0, stream>>>(emb, W1, b1, W2, b2, W3, b3, Y);

  // 128 rows per 1024-thread block, 2 blocks/CU.
  gather_sum_kernel<<<B / 128, 1024, 0, stream>>>(x, Y, (float*)d_out);
}

// Round 13
// 160.706 us; speedup vs baseline: 1.4778x; 1.4778x over previous
//
#include <hip/hip_runtime.h>
#include <hip/hip_fp16.h>

// Problem constants (from the reference).
constexpr int S  = 51;   // seq positions
constexpr int V  = 64;   // vocab
constexpr int E  = 4;    // embedding dim
constexpr int H1 = 5;
constexpr int H2 = 7;
constexpr int D  = 64;   // output dim

constexpr int CH   = 3;    // s-slices per staged chunk (24 KB)
constexpr int NC   = 17;   // 17 * 3 = 51 exactly, no tail
constexpr int RPB  = 128;  // batch rows per block
constexpr int TPAD = 52;   // padded token stride (8 rg reads -> 8 distinct banks)

// ---------------------------------------------------------------------------
// Kernel 1: build fp16 table Y[s][v][d] = tanh(W3[s] @ h2(s,v) + b3[s]).
// Whole MLP depends only on (s, token): 3264 rows x 64 d, 408 KB fp16.
// ---------------------------------------------------------------------------
__global__ void build_table_kernel(const float* __restrict__ emb,
                                   const float* __restrict__ W1,
                                   const float* __restrict__ b1,
                                   const float* __restrict__ W2,
                                   const float* __restrict__ b2,
                                   const float* __restrict__ W3,
                                   const float* __restrict__ b3,
                                   __half* __restrict__ Y) {
  const int sv = blockIdx.x;     // sv = s*64 + v
  const int s  = sv >> 6;
  const int d  = threadIdx.x;    // 0..63

  float e[E];
#pragma unroll
  for (int i = 0; i < E; ++i) e[i] = emb[sv * E + i];

  float h1[H1];
#pragma unroll
  for (int h = 0; h < H1; ++h) {
    float a = b1[s * H1 + h];
#pragma unroll
    for (int i = 0; i < E; ++i) a = fmaf(W1[(s * H1 + h) * E + i], e[i], a);
    h1[h] = (a >= 0.f) ? a : 0.01f * a;   // leaky_relu
  }

  float h2[H2];
#pragma unroll
  for (int g = 0; g < H2; ++g) {
    float a = b2[s * H2 + g];
#pragma unroll
    for (int h = 0; h < H1; ++h) a = fmaf(W2[(s * H2 + g) * H1 + h], h1[h], a);
    h2[g] = (a >= 0.f) ? a : 0.01f * a;
  }

  float a = b3[s * D + d];
#pragma unroll
  for (int g = 0; g < H2; ++g) a = fmaf(W3[(s * D + d) * H2 + g], h2[g], a);

  Y[sv * D + d] = __float2half(tanhf(a));
}

// ---------------------------------------------------------------------------
// Direct global -> LDS DMA, 16 B per lane (dest = uniform base + lane*16).
// No VGPR round-trip: kills the round-10 scratch-spill failure mode.
// ---------------------------------------------------------------------------
__device__ __forceinline__ void gload_lds16(const void* g, void* l) {
  __builtin_amdgcn_global_load_lds(
      (const __attribute__((address_space(1))) unsigned int*)g,
      (__attribute__((address_space(3))) unsigned int*)l, 16, 0, 0);
}

// ---------------------------------------------------------------------------
// Kernel 2: out[b][d] = sum_s Y[s, x[b,s], d]  -- LDS gather, spill-proof.
// 1024 threads (16 waves), 128 rows/block, 512 blocks. LDS 75.8 KB/block ->
// 2 blocks/CU (151.5 <= 160 KB) when VGPR <= 64. Tokens in LDS (pad-52:
// the 8 rg broadcast-reads land on 8 distinct banks). Table double-buffered
// in chunks of 3 s-slices (24 KB), staged by global_load_lds (24 x 1KB
// stripes: wave w does stripes w and w+16). One barrier per chunk drains
// vmcnt -> next buffer ready; in-flight loads hide under compute.
// Inner (lane = rg*8+li <-> row wid*8+rg, d-octet li), per s:
// ds_read_b32 token + ds_read_b128 table (octet covers all 32 banks) +
// 4 v_pk_add_f16; fp32 promote per chunk (3 s).
// No runtime-indexed register arrays anywhere (rule #20).
// ---------------------------------------------------------------------------
__global__ __launch_bounds__(1024, 4) void gather_sum_kernel(
    const int* __restrict__ x, const __half* __restrict__ Y,
    float* __restrict__ out) {
  __shared__ __align__(16) __half buf[2][CH * V * D];   // 2 x 24,576 B
  __shared__ int tokl[RPB * TPAD];                      // 26,624 B (75.8 KB total)

  const int tid  = threadIdx.x;
  const int lane = tid & 63;
  const int li   = lane & 7;         // d-octet 0..7
  const int rg   = lane >> 3;        // row-in-wave 0..7
  const int wid  = tid >> 6;         // wave 0..15
  const int rowbase = blockIdx.x * RPB;

  // Stage tokens as table-row BYTE offsets (t*128). Coalesced read of x.
  for (int i = tid; i < RPB * S; i += 1024) {
    const int r = i / S;
    const int s = i - r * S;
    tokl[r * TPAD + s] = x[rowbase * S + i] << 7;
  }

  const char* bufb = (const char*)buf;
  const char* Yb   = (const char*)Y;
  const int   li16 = li << 4;
  const int   trow = ((wid << 3) | rg) * TPAD;   // this lane's token row base

  // Stage chunk 0: 24 stripes of 1 KB over 16 waves.
  {
    const char* src = Yb;
    char* dst = (char*)buf[0];
    gload_lds16(src + wid * 1024 + lane * 16, dst + wid * 1024);
    if (wid < 8)
      gload_lds16(src + (wid + 16) * 1024 + lane * 16, dst + (wid + 16) * 1024);
  }

  float acc[8];
#pragma unroll
  for (int k = 0; k < 8; ++k) acc[k] = 0.f;

  for (int c = 0; c < NC; ++c) {
    __syncthreads();   // drains vmcnt: chunk c landed; prior reads of other buf done

    // Issue DMA for chunk c+1 into the other buffer (in flight during compute).
    if (c + 1 < NC) {
      const char* src = Yb + (c + 1) * (CH * V * D * 2);
      char* dst = (char*)buf[(c + 1) & 1];
      gload_lds16(src + wid * 1024 + lane * 16, dst + wid * 1024);
      if (wid < 8)
        gload_lds16(src + (wid + 16) * 1024 + lane * 16, dst + (wid + 16) * 1024);
    }

    // Compute chunk c from buf[c&1].
    const char* base = bufb + ((c & 1) ? (CH * V * D * 2) : 0);
    const int sbase = c * CH;

    __half2 a16[4];
#pragma unroll
    for (int k = 0; k < 4; ++k) a16[k] = __half2(__float2half(0.f), __float2half(0.f));

#pragma unroll
    for (int j = 0; j < CH; ++j) {
      const int toff = tokl[trow + sbase + j];            // t<<7 (bank-spread)
      const uint4 v = *(const uint4*)(base + ((j << 13) + toff + li16));
      union { uint4 u; __half2 h[4]; } cv; cv.u = v;
#pragma unroll
      for (int k = 0; k < 4; ++k) a16[k] = __hadd2(a16[k], cv.h[k]);
    }

#pragma unroll
    for (int k = 0; k < 4; ++k) {
      const float2 f = __half22float2(a16[k]);
      acc[2 * k]     += f.x;
      acc[2 * k + 1] += f.y;
    }
  }

  // Epilogue: wave writes 8 rows x 256 B contiguous.
  const int row = rowbase + (wid << 3) + rg;
  float4* o = (float4*)(out + row * D + li * 8);
  o[0] = make_float4(acc[0], acc[1], acc[2], acc[3]);
  o[1] = make_float4(acc[4], acc[5], acc[6], acc[7]);
}

// ---------------------------------------------------------------------------
extern "C" void kernel_launch(void* const* d_in, const int* in_sizes, int n_in,
                              void* d_out, int out_size, void* d_ws, size_t ws_size,
                              hipStream_t stream) {
  const int*   x   = (const int*)d_in[0];
  const float* emb = (const float*)d_in[1];
  const float* W1  = (const float*)d_in[2];
  const float* b1  = (const float*)d_in[3];
  const float* W2  = (const float*)d_in[4];
  const float* b2  = (const float*)d_in[5];
  const float* W3  = (const float*)d_in[6];
  const float* b3  = (const float*)d_in[7];

  const int B = in_sizes[0] / S;          // 65536
  __half* Y = (__half*)d_ws;              // S*V*D halves = 417,792 bytes

  build_table_kernel<<<S * V, D, 0, stream>>>(emb, W1, b1, W2, b2, W3, b3, Y);

  // 128 rows per 1024-thread block.
  gather_sum_kernel<<<B / RPB, 1024, 0, stream>>>(x, Y, (float*)d_out);
}

// Round 14
// 101.493 us; speedup vs baseline: 2.3400x; 1.5834x over previous
//
#include <hip/hip_runtime.h>
#include <hip/hip_fp16.h>

// Problem constants (from the reference).
constexpr int S  = 51;   // seq positions
constexpr int V  = 64;   // vocab
constexpr int E  = 4;    // embedding dim
constexpr int H1 = 5;
constexpr int H2 = 7;
constexpr int D  = 64;   // output dim

constexpr int CH   = 4;    // s-slices per staged chunk (32 KB)
constexpr int NCF  = 12;   // full chunks; tail chunk has 3 slices (12*4+3 = 51)
constexpr int RPB  = 128;  // batch rows per block
constexpr int TPAD = 52;   // padded token stride (8 rg reads -> 8 distinct banks)

// ---------------------------------------------------------------------------
// Kernel 1: build fp16 table Y[s][v][d] = tanh(W3[s] @ h2(s,v) + b3[s]).
// Whole MLP depends only on (s, token): 3264 rows x 64 d, 408 KB fp16.
// ---------------------------------------------------------------------------
__global__ void build_table_kernel(const float* __restrict__ emb,
                                   const float* __restrict__ W1,
                                   const float* __restrict__ b1,
                                   const float* __restrict__ W2,
                                   const float* __restrict__ b2,
                                   const float* __restrict__ W3,
                                   const float* __restrict__ b3,
                                   __half* __restrict__ Y) {
  const int sv = blockIdx.x;     // sv = s*64 + v
  const int s  = sv >> 6;
  const int d  = threadIdx.x;    // 0..63

  float e[E];
#pragma unroll
  for (int i = 0; i < E; ++i) e[i] = emb[sv * E + i];

  float h1[H1];
#pragma unroll
  for (int h = 0; h < H1; ++h) {
    float a = b1[s * H1 + h];
#pragma unroll
    for (int i = 0; i < E; ++i) a = fmaf(W1[(s * H1 + h) * E + i], e[i], a);
    h1[h] = (a >= 0.f) ? a : 0.01f * a;   // leaky_relu
  }

  float h2[H2];
#pragma unroll
  for (int g = 0; g < H2; ++g) {
    float a = b2[s * H2 + g];
#pragma unroll
    for (int h = 0; h < H1; ++h) a = fmaf(W2[(s * H2 + g) * H1 + h], h1[h], a);
    h2[g] = (a >= 0.f) ? a : 0.01f * a;
  }

  float a = b3[s * D + d];
#pragma unroll
  for (int g = 0; g < H2; ++g) a = fmaf(W3[(s * D + d) * H2 + g], h2[g], a);

  Y[sv * D + d] = __float2half(tanhf(a));
}

// ---------------------------------------------------------------------------
// Kernel 2: out[b][d] = sum_s Y[s, x[b,s], d]  -- LDS gather, CACHED staging.
// 1024 threads (16 waves), 128 rows/block, 512 blocks. LDS = 2x32KB table
// double-buffer + 13KB ushort tokens = 78.8 KB -> 2 blocks/CU.
// Staging via normal uint4 loads (L2-cached path: round-4 counters proved
// FETCH/WRITE stay clean, unlike global_load_lds DMA which bypassed L2 and
// caused round-13's 350 MB HBM traffic). Async-split: issue 2 loads for
// chunk c+1 right after the barrier, compute chunk c (hides L2 latency),
// ds_write late. Chunk-12 staging over-reads 16 KB into d_ws poison
// (in-bounds; lands in unused slice 3, never consumed) to stay branch-free.
// Tokens in LDS as ushort byte-offsets (t<<7 <= 8064), pad-52 -> the 8 rg
// broadcast-reads hit 8 distinct banks. Inner per (row,s): ds_read_u16 +
// ds_read_b128 (octet covers 128 B -> full bank spread) + 4 v_pk_add_f16;
// fp32 promote per chunk. No runtime-indexed register arrays (rule #20).
// ---------------------------------------------------------------------------
__global__ __launch_bounds__(1024, 8) void gather_sum_kernel(
    const int* __restrict__ x, const __half* __restrict__ Y,
    float* __restrict__ out) {
  __shared__ __align__(16) __half buf[2][CH * V * D];   // 2 x 32,768 B
  __shared__ unsigned short tokl[RPB * TPAD];           // 13,312 B (78.8 KB)

  const int tid  = threadIdx.x;
  const int lane = tid & 63;
  const int li   = lane & 7;         // d-octet 0..7
  const int rg   = lane >> 3;        // row-in-wave 0..7
  const int wid  = tid >> 6;         // wave 0..15
  const int rowbase = blockIdx.x * RPB;

  // Stage tokens as table-row BYTE offsets (t*128, fits ushort). Coalesced x.
  for (int i = tid; i < RPB * S; i += 1024) {
    const int r = i / S;
    const int s = i - r * S;
    tokl[r * TPAD + s] = (unsigned short)(x[rowbase * S + i] << 7);
  }

  const uint4* Yg   = (const uint4*)Y;          // 16B granules; 2048 per chunk
  const char*  bufb = (const char*)buf;
  const int    li16 = li << 4;
  const int    trow = ((wid << 3) | rg) * TPAD; // this lane's token row base

  // Prologue: stage chunk 0 (2048 granules, 2 per thread).
  {
    const uint4 t0 = Yg[tid];
    const uint4 t1 = Yg[tid + 1024];
    uint4* d = (uint4*)buf[0];
    d[tid]        = t0;
    d[tid + 1024] = t1;
  }

  float acc[8];
#pragma unroll
  for (int k = 0; k < 8; ++k) acc[k] = 0.f;

  for (int c = 0; c < NCF; ++c) {
    __syncthreads();   // chunk c staged; prior reads of buf[(c+1)&1] done

    // Issue cached loads for chunk c+1 (c=11 over-reads into ws poison:
    // in-bounds, lands in unused slice 3 of the tail chunk).
    const uint4* src = Yg + (c + 1) * 2048;
    const uint4 v0 = src[tid];
    const uint4 v1 = src[tid + 1024];

    // Compute chunk c from buf[c&1].
    __half2 a16[4];
#pragma unroll
    for (int k = 0; k < 4; ++k) a16[k] = __half2(__float2half(0.f), __float2half(0.f));

    const char* base = bufb + ((c & 1) << 15);
    const int   srow = trow + c * CH;
#pragma unroll
    for (int j = 0; j < CH; ++j) {
      const int toff = tokl[srow + j];                    // t<<7 (bank-spread)
      const uint4 v = *(const uint4*)(base + ((j << 13) + toff + li16));
      union { uint4 u; __half2 h[4]; } cv; cv.u = v;
#pragma unroll
      for (int k = 0; k < 4; ++k) a16[k] = __hadd2(a16[k], cv.h[k]);
    }
#pragma unroll
    for (int k = 0; k < 4; ++k) {
      const float2 f = __half22float2(a16[k]);
      acc[2 * k]     += f.x;
      acc[2 * k + 1] += f.y;
    }

    // Late LDS write of chunk c+1 (loads had the whole compute to land).
    uint4* d = (uint4*)buf[(c + 1) & 1];
    d[tid]        = v0;
    d[tid + 1024] = v1;
  }

  // Tail chunk (c = 12, 3 slices) from buf[0].
  __syncthreads();
  {
    __half2 a16[4];
#pragma unroll
    for (int k = 0; k < 4; ++k) a16[k] = __half2(__float2half(0.f), __float2half(0.f));

    const int srow = trow + NCF * CH;
#pragma unroll
    for (int j = 0; j < 3; ++j) {
      const int toff = tokl[srow + j];
      const uint4 v = *(const uint4*)(bufb + ((j << 13) + toff + li16));
      union { uint4 u; __half2 h[4]; } cv; cv.u = v;
#pragma unroll
      for (int k = 0; k < 4; ++k) a16[k] = __hadd2(a16[k], cv.h[k]);
    }
#pragma unroll
    for (int k = 0; k < 4; ++k) {
      const float2 f = __half22float2(a16[k]);
      acc[2 * k]     += f.x;
      acc[2 * k + 1] += f.y;
    }
  }

  // Epilogue: wave writes 8 rows x 256 B contiguous.
  const int row = rowbase + (wid << 3) + rg;
  float4* o = (float4*)(out + row * D + li * 8);
  o[0] = make_float4(acc[0], acc[1], acc[2], acc[3]);
  o[1] = make_float4(acc[4], acc[5], acc[6], acc[7]);
}

// ---------------------------------------------------------------------------
extern "C" void kernel_launch(void* const* d_in, const int* in_sizes, int n_in,
                              void* d_out, int out_size, void* d_ws, size_t ws_size,
                              hipStream_t stream) {
  const int*   x   = (const int*)d_in[0];
  const float* emb = (const float*)d_in[1];
  const float* W1  = (const float*)d_in[2];
  const float* b1  = (const float*)d_in[3];
  const float* W2  = (const float*)d_in[4];
  const float* b2  = (const float*)d_in[5];
  const float* W3  = (const float*)d_in[6];
  const float* b3  = (const float*)d_in[7];

  const int B = in_sizes[0] / S;          // 65536
  __half* Y = (__half*)d_ws;              // S*V*D halves = 417,792 bytes

  build_table_kernel<<<S * V, D, 0, stream>>>(emb, W1, b1, W2, b2, W3, b3, Y);

  // 128 rows per 1024-thread block.
  gather_sum_kernel<<<B / RPB, 1024, 0, stream>>>(x, Y, (float*)d_out);
}